// Round 5
// baseline (1313.440 us; speedup 1.0000x reference)
//
#include <hip/hip_runtime.h>
#include <math.h>

// Problem constants
#define HO 512
#define WO 512
#define HI 128
#define WI 128
#define CC 64      // channels
#define BS 2       // batch
#define NPX 64     // pixels per block (one row segment)
#define NT 256     // threads per block

// d_ws layout:
//   [0)              bf16 packed weights: w2p then w3p
//   [XT_ELEM_OFF)    x_t padded transpose: float [130][130][2][64]
#define W2P_ELEMS (16 * 2 * 64 * 8)      // [nt=16][ks=2][lane=64][j=8]
#define W3P_ELEMS (36 * 8 * 64 * 8)      // [nt=36][ks=8][lane=64][j=8], nt = ct*9+tap
#define XT_ELEM_OFF (W2P_ELEMS + W3P_ELEMS)     // in shorts (163840 -> 327680 B)
#define XT_FLOATS (130 * 130 * 128)             // 8.65 MB

typedef __attribute__((ext_vector_type(8))) short short8;
typedef __attribute__((ext_vector_type(4))) float float4v;

__device__ __forceinline__ unsigned short f2bf(float f) {
    unsigned u = __builtin_bit_cast(unsigned, f);
    unsigned r = (u + 0x7FFFu + ((u >> 16) & 1u)) >> 16;   // RNE
    return (unsigned short)r;
}

// ---------------- k1: pack weights to MFMA-B order + zero x_t ----------------
// B-frag (16x16x32): lane l holds B[n=l&15][k=(l>>4)*8+j], j=0..7
// W3 n-tile nt = ct*9 + tap: covers W3 rows (ct*16 + (l&15))*9 + tap
__global__ void prepack_zw(const float* __restrict__ W2,
                           const float* __restrict__ W3,
                           unsigned short* __restrict__ wsp,
                           float* __restrict__ xt) {
    const int total = W2P_ELEMS + W3P_ELEMS;
    for (int idx = blockIdx.x * blockDim.x + threadIdx.x; idx < total;
         idx += gridDim.x * blockDim.x) {
        float v;
        if (idx < W2P_ELEMS) {
            int j = idx & 7, lane = (idx >> 3) & 63, rest = idx >> 9;
            int ks = rest & 1, nt = rest >> 1;
            int n = nt * 16 + (lane & 15);
            int k = ks * 32 + (lane >> 4) * 8 + j;
            v = W2[n * 64 + k];                      // W2: [256][64]
        } else {
            int i2 = idx - W2P_ELEMS;
            int j = i2 & 7, lane = (i2 >> 3) & 63, rest = i2 >> 9;
            int ks = rest & 7, nt = rest >> 3;       // nt = ct*9 + tap
            int ct = nt / 9, tap = nt - ct * 9;
            int row = (ct * 16 + (lane & 15)) * 9 + tap;   // < 576
            int k = ks * 32 + (lane >> 4) * 8 + j;
            v = W3[row * 256 + k];                   // W3: [576][256]
        }
        wsp[idx] = f2bf(v);
    }
    // zero x_t (borders stay zero)
    float4v z = {0.f, 0.f, 0.f, 0.f};
    float4v* xt4 = (float4v*)xt;
    for (int i = blockIdx.x * blockDim.x + threadIdx.x; i < XT_FLOATS / 4;
         i += gridDim.x * blockDim.x)
        xt4[i] = z;
}

// ---------------- k2: x -> x_t[(h+1)][(w+1)][b][c] (interior) ----------------
__global__ void prepack_x(const float* __restrict__ x, float* __restrict__ xt) {
    const int tid = blockIdx.x * blockDim.x + threadIdx.x;
    const int pos = tid & 16383;          // h*128+w
    const int g   = tid >> 14;            // bc group: 8 channels
    const int h = pos >> 7, w = pos & 127;
    const float* src = x + pos;
    float4v v0, v1;
    #pragma unroll
    for (int j = 0; j < 4; ++j) v0[j] = src[(size_t)(g * 8 + j) * (HI * WI)];
    #pragma unroll
    for (int j = 0; j < 4; ++j) v1[j] = src[(size_t)(g * 8 + 4 + j) * (HI * WI)];
    float* dst = xt + ((h + 1) * 130 + (w + 1)) * 128 + g * 8;
    *(float4v*)dst = v0;
    *(float4v*)(dst + 4) = v1;
}

// ---------------- fused main kernel ----------------
// Per block: 64 pixels (one output-row segment), 4 waves.
// stage1 (VALU): h1[64][64] -> LDS bf16 (region R)
// stage2 (MFMA): per wave, its 16 px: h2 -> sH2 (R, overwrites sH1 after
//                A-frags are register-resident + barrier)
// stage3 (MFMA): wave wv owns channel-tile ct=wv (16 ch), computes ALL 64 px
//                in 2 m-passes of 2 m-tiles -> each W3 B-frag feeds 2 MFMAs,
//                halving per-block W3 L1 traffic. 9 tap logits per (ch,px) in
//                registers -> softmax in regs -> coalesced gather from x_t.
// epilogue: outputs (32 regs) -> sOut transpose (aliases R) -> coalesced store
__global__ __launch_bounds__(NT, 4)
void fused_main(const float* __restrict__ xt, const float* __restrict__ pose,
                const float* __restrict__ W1, const float* __restrict__ b1,
                const float* __restrict__ b2, const float* __restrict__ b3,
                const int* __restrict__ iY, const int* __restrict__ iX,
                const unsigned short* __restrict__ wsp,
                float* __restrict__ out)
{
    // Region R (34816 B) holds, in temporal sequence:
    //   sH1 [64][72] bf16 (9216 B) -> sH2 [64][264] bf16 (33792 B)
    //   -> sOut [4][2][16][68] float (34816 B)
    __shared__ char smem[34816 + 768 + 256 + 256];   // 36096 B -> 4 blocks/CU
    unsigned short (*sH1)[72]  = (unsigned short (*)[72])&smem[0];
    unsigned short (*sH2)[264] = (unsigned short (*)[264])&smem[0];
    float (*sOut)[2][16][68]   = (float (*)[2][16][68])&smem[0];
    float (*sP)[NPX]           = (float (*)[NPX])&smem[34816];
    int* sIY                   = (int*)&smem[35584];
    int* sIX                   = (int*)&smem[35840];

    const int t = threadIdx.x;
    const int pixBase = blockIdx.x * NPX;    // 64 px within one output row
    const int y  = pixBase / WO;
    const int x0 = pixBase % WO;

    if (t < 192) sP[t >> 6][t & 63] = pose[(t >> 6) * (HO * WO) + pixBase + (t & 63)];
    if (t < 64) sIY[t] = iY[pixBase + t];
    else if (t < 128) sIX[t - 64] = iX[pixBase + t - 64];
    __syncthreads();

    // ---- stage 1: h1 = relu(W1 @ p + b1) -> sH1
    {
        const int p  = t & 63;
        const int og = t >> 6;
        const float p0 = sP[0][p], p1 = sP[1][p], p2 = sP[2][p];
        #pragma unroll
        for (int i = 0; i < 16; i += 2) {
            const int o = og * 16 + i;
            float a0 = fmaf(W1[o * 3 + 2], p2, fmaf(W1[o * 3 + 1], p1, fmaf(W1[o * 3 + 0], p0, b1[o])));
            float a1 = fmaf(W1[o * 3 + 5], p2, fmaf(W1[o * 3 + 4], p1, fmaf(W1[o * 3 + 3], p0, b1[o + 1])));
            a0 = fmaxf(a0, 0.f); a1 = fmaxf(a1, 0.f);
            unsigned pack = (unsigned)f2bf(a0) | ((unsigned)f2bf(a1) << 16);
            *(unsigned*)&sH1[p][o] = pack;
        }
    }
    __syncthreads();

    const int wv = t >> 6, l = t & 63, lm = l & 15, lq = l >> 4;
    const int m0 = wv * 16;                  // wave's pixel base (stage 2)

    // A-frags for stage2 into registers BEFORE sH1 region is overwritten
    short8 h1a0 = *(const short8*)&sH1[m0 + lm][0  + lq * 8];
    short8 h1a1 = *(const short8*)&sH1[m0 + lm][32 + lq * 8];
    __syncthreads();   // all waves hold h1 frags; R may be rewritten as sH2

    // ---- stage 2: h2 = relu(h1 @ W2^T + b2)  [16px x 256] per wave -> sH2
    {
        const short8* w2f = (const short8*)wsp;
        #pragma unroll 4
        for (int nt = 0; nt < 16; ++nt) {
            float4v acc = {0.f, 0.f, 0.f, 0.f};
            short8 bf0 = w2f[(nt * 2 + 0) * 64 + l];
            short8 bf1 = w2f[(nt * 2 + 1) * 64 + l];
            acc = __builtin_amdgcn_mfma_f32_16x16x32_bf16(h1a0, bf0, acc, 0, 0, 0);
            acc = __builtin_amdgcn_mfma_f32_16x16x32_bf16(h1a1, bf1, acc, 0, 0, 0);
            const float bv = b2[nt * 16 + lm];
            #pragma unroll
            for (int r = 0; r < 4; ++r)
                sH2[m0 + lq * 4 + r][nt * 16 + lm] = f2bf(fmaxf(acc[r] + bv, 0.f));
        }
    }
    __syncthreads();

    // ---- stage 3: wave wv owns ct = wv; all 64 px in 2 passes x 2 m-tiles
    const int c = wv * 16 + lm;              // lane's channel (fixed)
    const short8* w3w = ((const short8*)(wsp + W2P_ELEMS)) + (size_t)wv * (9 * 8 * 64);
    const int koff[9] = {-131 * 128, -130 * 128, -129 * 128,
                         -1 * 128,   0,          1 * 128,
                         129 * 128,  130 * 128,  131 * 128};
    float bv[9];
    #pragma unroll
    for (int tap = 0; tap < 9; ++tap) bv[tap] = b3[c * 9 + tap];

    float oreg[2][2][4][2];                  // [pass][mt][r][b]

    #pragma unroll
    for (int pass = 0; pass < 2; ++pass) {
        float4v acc0[9], acc1[9];
        #pragma unroll
        for (int tap = 0; tap < 9; ++tap) {
            acc0[tap] = (float4v){0.f, 0.f, 0.f, 0.f};
            acc1[tap] = (float4v){0.f, 0.f, 0.f, 0.f};
        }
        #pragma unroll 2
        for (int ks = 0; ks < 8; ++ks) {
            short8 a0 = *(const short8*)&sH2[pass * 32 + lm][ks * 32 + lq * 8];
            short8 a1 = *(const short8*)&sH2[pass * 32 + 16 + lm][ks * 32 + lq * 8];
            #pragma unroll
            for (int tap = 0; tap < 9; ++tap) {
                short8 b = w3w[(tap * 8 + ks) * 64 + l];
                acc0[tap] = __builtin_amdgcn_mfma_f32_16x16x32_bf16(a0, b, acc0[tap], 0, 0, 0);
                acc1[tap] = __builtin_amdgcn_mfma_f32_16x16x32_bf16(a1, b, acc1[tap], 0, 0, 0);
            }
        }
        // epilogue: softmax in regs + gather; D layout: col=lm(ch), row=lq*4+r(px)
        #pragma unroll
        for (int mt = 0; mt < 2; ++mt) {
            #pragma unroll
            for (int r = 0; r < 4; ++r) {
                const int px = pass * 32 + mt * 16 + lq * 4 + r;
                float lg[9];
                #pragma unroll
                for (int tap = 0; tap < 9; ++tap)
                    lg[tap] = (mt == 0 ? acc0[tap][r] : acc1[tap][r]) + bv[tap];
                float mx = lg[0];
                #pragma unroll
                for (int tap = 1; tap < 9; ++tap) mx = fmaxf(mx, lg[tap]);
                const float* xb = xt + ((sIY[px] + 1) * 130 + (sIX[px] + 1)) * 128 + c;
                float s = 0.f, o0 = 0.f, o1 = 0.f;
                #pragma unroll
                for (int tap = 0; tap < 9; ++tap) {
                    const float ev = __expf(lg[tap] - mx);
                    s += ev;
                    o0 = fmaf(ev, xb[koff[tap]], o0);        // b=0, 16ch coalesced
                    o1 = fmaf(ev, xb[koff[tap] + 64], o1);   // b=1
                }
                const float inv = 1.f / s;
                oreg[pass][mt][r][0] = o0 * inv;
                oreg[pass][mt][r][1] = o1 * inv;
            }
        }
    }

    __syncthreads();   // all waves done reading sH2 -> R becomes sOut

    #pragma unroll
    for (int pass = 0; pass < 2; ++pass)
        #pragma unroll
        for (int mt = 0; mt < 2; ++mt)
            #pragma unroll
            for (int b = 0; b < 2; ++b)
                *(float4v*)&sOut[wv][b][lm][pass * 32 + mt * 16 + lq * 4] =
                    (float4v){oreg[pass][mt][0][b], oreg[pass][mt][1][b],
                              oreg[pass][mt][2][b], oreg[pass][mt][3][b]};
    __syncthreads();   // cross-lane handoff (R2 lesson)

    // coalesced store: thread pair (half 0/1) covers one (b,ch) 64-px row
    {
        const int row = t >> 1, half = t & 1;
        const int wvp = row >> 5, bb = (row >> 4) & 1, ch = row & 15;
        const float* sop = &sOut[wvp][bb][ch][half * 32];
        float* op = out + (((size_t)(bb * CC + wvp * 16 + ch) * HO) + y) * WO
                    + x0 + half * 32;
        #pragma unroll
        for (int k = 0; k < 8; ++k)
            *(float4v*)&op[k * 4] = *(const float4v*)&sop[k * 4];
    }
}

extern "C" void kernel_launch(void* const* d_in, const int* in_sizes, int n_in,
                              void* d_out, int out_size, void* d_ws, size_t ws_size,
                              hipStream_t stream) {
    const float* x    = (const float*)d_in[0];
    const float* pose = (const float*)d_in[1];
    const float* W1   = (const float*)d_in[2];
    const float* b1   = (const float*)d_in[3];
    const float* W2   = (const float*)d_in[4];
    const float* b2   = (const float*)d_in[5];
    const float* W3   = (const float*)d_in[6];
    const float* b3   = (const float*)d_in[7];
    const int*   iY   = (const int*)d_in[8];
    const int*   iX   = (const int*)d_in[9];
    float* out = (float*)d_out;
    unsigned short* wsp = (unsigned short*)d_ws;
    float* xt = (float*)((char*)d_ws + XT_ELEM_OFF * sizeof(unsigned short));

    prepack_zw<<<2048, NT, 0, stream>>>(W2, W3, wsp, xt);
    prepack_x<<<1024, NT, 0, stream>>>(x, xt);

    const int nblocks = (HO * WO) / NPX;   // 4096
    fused_main<<<nblocks, NT, 0, stream>>>(
        xt, pose, W1, b1, b2, b3, iY, iX, wsp, out);
}